// Round 4
// baseline (769.109 us; speedup 1.0000x reference)
//
#include <hip/hip_runtime.h>
#include <math.h>

#define BSZ 256
#define DIM 1024
#define VOC 50257
#define NL 2
#define NB 8
#define DH 128

typedef __bf16 bf16x8 __attribute__((ext_vector_type(8)));
typedef float  f32x4  __attribute__((ext_vector_type(4)));
typedef unsigned short u16;
typedef u16 u16x8 __attribute__((ext_vector_type(8)));

typedef __attribute__((address_space(1))) const void gvoid;
typedef __attribute__((address_space(3))) void lvoid;
#define GLOAD_LDS(g, l) __builtin_amdgcn_global_load_lds((gvoid*)(g), (lvoid*)(l), 16, 0, 0)

__device__ __forceinline__ u16 f2bf(float f) {
  unsigned int u = __float_as_uint(f);
  u += 0x7fffu + ((u >> 16) & 1u);   // RNE
  return (u16)(u >> 16);
}
__device__ __forceinline__ float sigm(float x) { return 1.0f / (1.0f + __expf(-x)); }

// ---------------------------------------------------------------------------
// m97-style block GEMM core: acc[4][4] += A(256 x K bf16, lda) * B^T where
// B = 64 rows x K fp32 (ldb). 256 threads; wave w computes A-rows w*64..+63.
// B tile double-buffered in LDS via async global_load_lds (width 16), fp32,
// XOR-swizzled at 16B granularity via the GLOBAL source address (key=row&15)
// so fragment ds_reads are 2-way-bank-aliased (free). f32->bf16 on LDS read.
// ---------------------------------------------------------------------------
template<bool CLAMP>
__device__ __forceinline__ void lds_gemm(
    const u16* __restrict__ A, int lda,
    const float* __restrict__ Btile, int ldb, int rowsLeft, int K,
    float* sB0, float* sB1, f32x4 (&acc)[4][4])
{
  const int tid  = threadIdx.x;
  const int wave = tid >> 6;
  const int lane = tid & 63;
  const int quad = lane >> 4;
  const int l16  = lane & 15;

  // Per-thread staging source: thread j stages 16B-unit (row = j>>4, c' = j&15),
  // whose swizzled global column unit is c' ^ (row & 15).
  const int srow = tid >> 4;
  const int scp  = tid & 15;

#define STAGE(sX, kb)                                                       \
  {                                                                         \
    _Pragma("unroll")                                                       \
    for (int p = 0; p < 4; ++p) {                                           \
      int row = p * 16 + srow;                                              \
      int r = row;                                                          \
      if (CLAMP) r = (r < rowsLeft) ? r : (rowsLeft - 1);                   \
      const float* g = Btile + (long)r * ldb + (kb) + ((scp ^ (row & 15)) << 2); \
      GLOAD_LDS(g, (sX) + (p * 256 + tid) * 4);                             \
    }                                                                       \
  }

  STAGE(sB0, 0);
  const u16* Abase = A + (long)(wave * 64 + l16) * lda + quad * 8;

#pragma unroll 1
  for (int kb = 0; kb < K; kb += 64) {
    float* cur = ((kb >> 6) & 1) ? sB1 : sB0;
    float* nxt = ((kb >> 6) & 1) ? sB0 : sB1;
    if (kb + 64 < K) STAGE(nxt, kb + 64);
    __syncthreads();
#pragma unroll
    for (int kk = 0; kk < 64; kk += 32) {
      // A fragments first (global, long latency)
      bf16x8 aF[4];
#pragma unroll
      for (int mi = 0; mi < 4; ++mi)
        aF[mi] = *(const bf16x8*)(Abase + (long)mi * 16 * lda + kb + kk);
      // B fragments from swizzled LDS, fp32 -> bf16
      bf16x8 bF[4];
#pragma unroll
      for (int ni = 0; ni < 4; ++ni) {
        int r = ni * 16 + l16;
        int u0 = (kk >> 2) + quad * 2;
        const float* base = cur + r * 64;
        float4 v0 = *(const float4*)(base + (((u0    ) ^ l16) << 2));
        float4 v1 = *(const float4*)(base + (((u0 + 1) ^ l16) << 2));
        u16x8 h;
        h[0] = f2bf(v0.x); h[1] = f2bf(v0.y); h[2] = f2bf(v0.z); h[3] = f2bf(v0.w);
        h[4] = f2bf(v1.x); h[5] = f2bf(v1.y); h[6] = f2bf(v1.z); h[7] = f2bf(v1.w);
        bF[ni] = __builtin_bit_cast(bf16x8, h);
      }
#pragma unroll
      for (int mi = 0; mi < 4; ++mi)
#pragma unroll
        for (int ni = 0; ni < 4; ++ni)
          acc[mi][ni] = __builtin_amdgcn_mfma_f32_16x16x32_bf16(aF[mi], bF[ni], acc[mi][ni], 0, 0, 0);
    }
    __syncthreads();
  }
#undef STAGE
}

#define GEMM_SHARED                                   \
  __shared__ float sB0[64 * 64];                      \
  __shared__ float sB1[64 * 64];

#define ACC_DECL                                      \
  f32x4 acc[4][4];                                    \
  { f32x4 z = {0.f, 0.f, 0.f, 0.f};                   \
    _Pragma("unroll")                                 \
    for (int i = 0; i < 4; ++i)                       \
      _Pragma("unroll")                               \
      for (int j = 0; j < 4; ++j) acc[i][j] = z; }

#define IDX_DECL                                      \
  const int tid = threadIdx.x;                        \
  const int wave = tid >> 6;                          \
  const int quad = (tid >> 4) & 3;                    \
  const int l16 = tid & 15;

// ---------------------------------------------------------------------------
// K1: carry (bool-layout detect), x gather (fp32 + bf16), h -> bf16
// ---------------------------------------------------------------------------
__global__ __launch_bounds__(256) void k_prep(
    const int* __restrict__ ids, const void* __restrict__ mask,
    const float* __restrict__ emb, const float* __restrict__ hstate,
    float* __restrict__ xout, u16* __restrict__ x_bf,
    u16* __restrict__ h_bf, float* __restrict__ carry)
{
  __shared__ int sInt;
  const int tid = threadIdx.x, s = blockIdx.x;
  if (tid == 0) sInt = 1;
  __syncthreads();
  if (tid < 64) {
    int v = ((const int*)mask)[tid];
    if (v != 0 && v != 1) atomicAnd(&sInt, 0);
  }
  __syncthreads();
  if (tid == 0) {
    int m = sInt ? ((const int*)mask)[s] : (int)((const unsigned char*)mask)[s];
    carry[s] = m ? 0.0f : 1.0f;
  }
  long id = ids[s];
  int k = tid * 4;
  float4 v = *(const float4*)(emb + id * DIM + k);
  *(float4*)(xout + (long)s * DIM + k) = v;
  ushort4 h; h.x = f2bf(v.x); h.y = f2bf(v.y); h.z = f2bf(v.z); h.w = f2bf(v.w);
  *(ushort4*)(x_bf + (long)s * DIM + k) = h;
#pragma unroll
  for (int l = 0; l < NL; ++l) {
    long off = (long)l * BSZ * DIM + (long)s * DIM + k;
    float4 w = *(const float4*)(hstate + off);
    ushort4 o; o.x = f2bf(w.x); o.y = f2bf(w.y); o.z = f2bf(w.z); o.w = f2bf(w.w);
    *(ushort4*)(h_bf + off) = o;
  }
}

// ---------------------------------------------------------------------------
// K2: [alpha_pre | x_proj] = x @ [W_alpha ; W_in]^T, fused wm_new epilogue
// 32 blocks: first 16 alpha, next 16 x_proj (n-tile 64)
// ---------------------------------------------------------------------------
__global__ __launch_bounds__(256) void k_gemm1(
    const u16* __restrict__ x_bf,
    const float* __restrict__ W_alpha, const float* __restrict__ W_in,
    const float* __restrict__ carry, const float* __restrict__ wm_state,
    const float* __restrict__ xout,
    u16* __restrict__ wm_bf, u16* __restrict__ cur_bf)
{
  GEMM_SHARED
  IDX_DECL
  ACC_DECL
  const bool isAlpha = blockIdx.x < 16;
  const int n0 = (blockIdx.x & 15) * 64;
  lds_gemm<false>(x_bf, DIM, (isAlpha ? W_alpha : W_in) + (long)n0 * DIM, DIM, 64, DIM,
                  sB0, sB1, acc);
#pragma unroll
  for (int mi = 0; mi < 4; ++mi)
#pragma unroll
    for (int ni = 0; ni < 4; ++ni) {
      int n = n0 + ni * 16 + l16;
#pragma unroll
      for (int r = 0; r < 4; ++r) {
        int s = wave * 64 + mi * 16 + quad * 4 + r;
        float c = acc[mi][ni][r];
        long idx = (long)s * DIM + n;
        if (isAlpha) wm_bf[idx] = f2bf(carry[s] * sigm(c) * wm_state[idx] + xout[idx]);
        else         cur_bf[idx] = f2bf(c);
      }
    }
}

// ---------------------------------------------------------------------------
// K3: y_wm = tanh(wm_new @ W_wm_out^T)   (16 blocks)
// ---------------------------------------------------------------------------
__global__ __launch_bounds__(256) void k_gemm2(
    const u16* __restrict__ wm_bf, const float* __restrict__ W_wm_out,
    float* __restrict__ yout, u16* __restrict__ ywm_bf)
{
  GEMM_SHARED
  IDX_DECL
  ACC_DECL
  const int n0 = blockIdx.x * 64;
  lds_gemm<false>(wm_bf, DIM, W_wm_out + (long)n0 * DIM, DIM, 64, DIM, sB0, sB1, acc);
#pragma unroll
  for (int mi = 0; mi < 4; ++mi)
#pragma unroll
    for (int ni = 0; ni < 4; ++ni) {
      int n = n0 + ni * 16 + l16;
#pragma unroll
      for (int r = 0; r < 4; ++r) {
        int s = wave * 64 + mi * 16 + quad * 4 + r;
        float y = tanhf(acc[mi][ni][r]);
        long idx = (long)s * DIM + n;
        yout[idx] = y;
        ywm_bf[idx] = f2bf(y);
      }
    }
}

// ---------------------------------------------------------------------------
// K4/K6: a = cur@W_x^T + h@W_h^T + y_wm@W_wml^T  (16 blocks: 8 b x 2 n-tiles)
// ---------------------------------------------------------------------------
__global__ __launch_bounds__(256) void k_gemm_a(
    int l, const u16* __restrict__ cur_bf, const u16* __restrict__ h_bf,
    const u16* __restrict__ ywm_bf,
    const float* __restrict__ W_x, const float* __restrict__ W_h,
    const float* __restrict__ W_wml,
    float* __restrict__ a_f32, u16* __restrict__ a_bf)
{
  GEMM_SHARED
  IDX_DECL
  ACC_DECL
  const int b = blockIdx.x >> 1;
  const int n0 = (blockIdx.x & 1) * 64;
  lds_gemm<false>(cur_bf + b * DH, DIM,
                  W_x + ((long)(l * NB + b) * DH + n0) * DH, DH, 64, DH, sB0, sB1, acc);
  lds_gemm<false>(h_bf + (long)l * BSZ * DIM + b * DH, DIM,
                  W_h + ((long)(l * NB + b) * DH + n0) * DH, DH, 64, DH, sB0, sB1, acc);
  lds_gemm<false>(ywm_bf, DIM,
                  W_wml + ((long)(l * NB + b) * DH + n0) * DIM, DIM, 64, DIM, sB0, sB1, acc);
#pragma unroll
  for (int mi = 0; mi < 4; ++mi)
#pragma unroll
    for (int ni = 0; ni < 4; ++ni) {
      int e = n0 + ni * 16 + l16;
#pragma unroll
      for (int r = 0; r < 4; ++r) {
        int s = wave * 64 + mi * 16 + quad * 4 + r;
        float c = acc[mi][ni][r];
        long idx = (long)s * DIM + b * DH + e;
        a_f32[idx] = c;
        a_bf[idx] = f2bf(c);
      }
    }
}

// ---------------------------------------------------------------------------
// K5/K7: g = sigmoid(a@W_g^T + surprise*w_s + b_g); h_new gating  (16 blocks)
// ---------------------------------------------------------------------------
__global__ __launch_bounds__(256) void k_gemm_g(
    int l, const u16* __restrict__ a_bf, const float* __restrict__ W_g,
    const float* __restrict__ w_s, const float* __restrict__ b_g,
    const float* __restrict__ surprise, const float* __restrict__ carry,
    const float* __restrict__ hstate, const float* __restrict__ a_f32,
    u16* __restrict__ hout_bf)
{
  GEMM_SHARED
  IDX_DECL
  ACC_DECL
  const int b = blockIdx.x >> 1;
  const int n0 = (blockIdx.x & 1) * 64;
  lds_gemm<false>(a_bf + b * DH, DIM,
                  W_g + ((long)(l * NB + b) * DH + n0) * DH, DH, 64, DH, sB0, sB1, acc);
#pragma unroll
  for (int mi = 0; mi < 4; ++mi)
#pragma unroll
    for (int ni = 0; ni < 4; ++ni) {
      int e = n0 + ni * 16 + l16;
#pragma unroll
      for (int r = 0; r < 4; ++r) {
        int s = wave * 64 + mi * 16 + quad * 4 + r;
        float c = acc[mi][ni][r];
        long idx = (long)s * DIM + b * DH + e;
        float gp = c + surprise[s] * w_s[(l * NB + b) * DH + e] + b_g[(l * NB + b) * DH + e];
        float g = sigm(gp);
        float ho = hstate[(long)l * BSZ * DIM + idx];
        float hn = carry[s] * ((1.0f - g) * ho + g * tanhf(a_f32[idx]));
        hout_bf[idx] = f2bf(hn);
      }
    }
}

// ---------------------------------------------------------------------------
// K8: logits = h_final @ emb^T  (786 blocks, n-tile 64)
// ---------------------------------------------------------------------------
__global__ __launch_bounds__(256) void k_logits(
    const u16* __restrict__ hfin_bf, const float* __restrict__ emb,
    float* __restrict__ out)
{
  GEMM_SHARED
  IDX_DECL
  ACC_DECL
  const int n0 = blockIdx.x * 64;
  lds_gemm<true>(hfin_bf, DIM, emb + (long)n0 * DIM, DIM, VOC - n0, DIM, sB0, sB1, acc);
#pragma unroll
  for (int mi = 0; mi < 4; ++mi)
#pragma unroll
    for (int ni = 0; ni < 4; ++ni) {
      int n = n0 + ni * 16 + l16;
      if (n < VOC) {
#pragma unroll
        for (int r = 0; r < 4; ++r) {
          int s = wave * 64 + mi * 16 + quad * 4 + r;
          out[(long)s * VOC + n] = acc[mi][ni][r];
        }
      }
    }
}

extern "C" void kernel_launch(void* const* d_in, const int* in_sizes, int n_in,
                              void* d_out, int out_size, void* d_ws, size_t ws_size,
                              hipStream_t stream) {
  const int*   input_id = (const int*)d_in[0];
  const void*  reset    = d_in[1];
  const float* surprise = (const float*)d_in[2];
  const float* wm_state = (const float*)d_in[3];
  const float* h_state  = (const float*)d_in[4];
  const float* emb      = (const float*)d_in[5];
  const float* W_in     = (const float*)d_in[6];
  const float* W_alpha  = (const float*)d_in[7];
  const float* W_wm_out = (const float*)d_in[8];
  const float* W_x      = (const float*)d_in[9];
  const float* W_h      = (const float*)d_in[10];
  const float* W_wml    = (const float*)d_in[11];
  const float* W_g      = (const float*)d_in[12];
  const float* w_s      = (const float*)d_in[13];
  const float* b_g      = (const float*)d_in[14];

  float* out  = (float*)d_out;
  float* xout = out + (size_t)BSZ * VOC;          // x output (fp32, exact)
  float* yout = xout + (size_t)BSZ * DIM;         // y_wm output

  // Scratch lives in the logits region of d_out (only read before k_logits).
  const long SD = (long)BSZ * DIM;                // 262144
  u16* scr    = (u16*)d_out;
  u16* x_bf   = scr;                              // 256x1024
  u16* wm_bf  = scr + SD;
  u16* cur_bf = scr + 2 * SD;
  u16* ywm_bf = scr + 3 * SD;
  u16* h_bf   = scr + 4 * SD;                     // 2x256x1024
  u16* a_bf   = scr + 6 * SD;
  float* a_f32 = (float*)(scr + 8 * SD);          // 256x1024 fp32

  // h_final + carry live OUTSIDE d_out (read while k_logits writes d_out)
  float* carry  = (float*)d_ws;
  u16* hfin_bf  = (u16*)((char*)d_ws + 1024);

  k_prep<<<BSZ, 256, 0, stream>>>(input_id, reset, emb, h_state, xout, x_bf, h_bf, carry);
  k_gemm1<<<32, 256, 0, stream>>>(x_bf, W_alpha, W_in, carry, wm_state, xout, wm_bf, cur_bf);
  k_gemm2<<<16, 256, 0, stream>>>(wm_bf, W_wm_out, yout, ywm_bf);
  k_gemm_a<<<16, 256, 0, stream>>>(0, cur_bf, h_bf, ywm_bf, W_x, W_h, W_wml, a_f32, a_bf);
  k_gemm_g<<<16, 256, 0, stream>>>(0, a_bf, W_g, w_s, b_g, surprise, carry, h_state, a_f32, cur_bf);
  k_gemm_a<<<16, 256, 0, stream>>>(1, cur_bf, h_bf, ywm_bf, W_x, W_h, W_wml, a_f32, a_bf);
  k_gemm_g<<<16, 256, 0, stream>>>(1, a_bf, W_g, w_s, b_g, surprise, carry, h_state, a_f32, hfin_bf);
  k_logits<<<(VOC + 63) / 64, 256, 0, stream>>>(hfin_bf, emb, out);
}